// Round 4
// baseline (720.211 us; speedup 1.0000x reference)
//
#include <hip/hip_runtime.h>

#define LEAKY 0.2f

// Problem constants (from reference setup_inputs)
constexpr int H = 2, B = 2048, M = 32, Dd = 32;
constexpr int NSLOT = H * B * M;              // 131072
constexpr int N4_R  = NSLOT * 64;             // f32x4 elements of r_all... (see below)

// Kernel A shape: flat, fill-like. One thread per f32x4 of r_all.
// NSLOT * (1024 floats / 4) = NSLOT * 256 f32x4 = 33,554,432.
constexpr int RCOPY_N4      = NSLOT * 256;
constexpr int RCOPY_BLOCKS  = 2048;
constexpr int RCOPY_THREADS = 256;
constexpr int RCOPY_STRIDE  = RCOPY_BLOCKS * RCOPY_THREADS;   // 524288
constexpr int RCOPY_ITERS   = RCOPY_N4 / RCOPY_STRIDE;        // 64 exact

// True clang vector type — required by __builtin_nontemporal_{load,store}
typedef float f32x4 __attribute__((ext_vector_type(4)));

// ---------------------------------------------------------------------------
// Kernel 1: passthrough copies uEmbed -> out[0], iEmbed -> out[1]
// ---------------------------------------------------------------------------
__global__ void copy_ui_kernel(const f32x4* __restrict__ u,
                               const f32x4* __restrict__ it,
                               f32x4* __restrict__ out_u,
                               f32x4* __restrict__ out_i, int n4) {
    int i = blockIdx.x * blockDim.x + threadIdx.x;
    if (i < n4) {
        f32x4 uv = __builtin_nontemporal_load(&u[i]);
        f32x4 iv = __builtin_nontemporal_load(&it[i]);
        __builtin_nontemporal_store(uv, &out_u[i]);
        __builtin_nontemporal_store(iv, &out_i[i]);
    }
}

// ---------------------------------------------------------------------------
// Kernel 2: winner[pos_items[b]] = max b  (last-occurrence-wins scatter)
// ---------------------------------------------------------------------------
__global__ void winner_kernel(const int* __restrict__ pos,
                              int* __restrict__ winner, int n) {
    int i = blockIdx.x * blockDim.x + threadIdx.x;
    if (i < n) atomicMax(&winner[pos[i]], i);
}

// ---------------------------------------------------------------------------
// Kernel A: FLAT r_all stream + fused Rh. Fill-shaped: one thread = one f32x4.
// Global f32x4 index j:  slot = j>>8  (wave-uniform: 64 consecutive j per wave
// always lie inside one 256-aligned window),  o = j&255 = within-row f32x4.
//   - copy rel[ridx][o] -> out_r[j]   (NT store: pure output stream)
//   - Rh: float4 o covers row d = o>>3, cols e = (4o)&31 .. +3.
//     Lanes l..l+7 (8-aligned) share d; 3-round shfl_xor reduce; lane%8==0
//     stores Rh[slot][d].
// Per-thread cost: 1 L2 read, 1 NT store, 4 FMA, 3 shuffles. No divergence
// except the 1-in-8 Rh store. Unroll 4 => 4 independent read/store pairs
// in flight per thread.
// ---------------------------------------------------------------------------
__global__ __launch_bounds__(RCOPY_THREADS) void rcopy_rh_kernel(
    const int* __restrict__ mr, const int* __restrict__ mh,
    const float* __restrict__ ent, const float* __restrict__ rel,
    float* __restrict__ out_r, float* __restrict__ Rh) {
    const int tid  = blockIdx.x * RCOPY_THREADS + threadIdx.x;
    const int lane = threadIdx.x & 63;
    const int e0   = (lane * 4) & 31;   // h cols this lane's f32x4 touches
    const f32x4* rel4 = (const f32x4*)rel;
    f32x4*       out4 = (f32x4*)out_r;

#pragma unroll 4
    for (int it = 0; it < RCOPY_ITERS; ++it) {
        int j = tid + it * RCOPY_STRIDE;
        // slot is wave-uniform: force to SGPR so mr/mh become scalar loads
        int slot = __builtin_amdgcn_readfirstlane(j >> 8);
        int o    = j & 255;
        int ridx = mr[slot];
        int hidx = mh[slot];

        f32x4 v = rel4[(size_t)ridx * 256 + o];           // L2-resident table
        __builtin_nontemporal_store(v, &out4[j]);         // the 537 MB stream

        f32x4 hv = *(const f32x4*)(ent + (size_t)hidx * Dd + e0);
        float partial = v.x * hv.x + v.y * hv.y + v.z * hv.z + v.w * hv.w;
#pragma unroll
        for (int off = 1; off < 8; off <<= 1)
            partial += __shfl_xor(partial, off, 64);
        if ((lane & 7) == 0) {
            int d = o >> 3;
            Rh[(size_t)slot * Dd + d] = partial;          // cached: ripple reads
        }
    }
}

// ---------------------------------------------------------------------------
// Kernel B: h/t gather, flat. One thread = one f32x4 of h_all / t_all.
// i in [0, NSLOT*8): slot = i>>3, o = i&7.
// ---------------------------------------------------------------------------
__global__ __launch_bounds__(256) void ht_gather_kernel(
    const int* __restrict__ mh, const int* __restrict__ mt,
    const float* __restrict__ ent, float* __restrict__ out_h,
    float* __restrict__ out_t) {
    int i = blockIdx.x * blockDim.x + threadIdx.x;        // exact grid
    int slot = i >> 3, o = i & 7;
    int hidx = mh[slot], tidx = mt[slot];
    const f32x4* ent4 = (const f32x4*)ent;

    f32x4 hv = __builtin_nontemporal_load(&ent4[(size_t)hidx * 8 + o]);
    __builtin_nontemporal_store(hv, &((f32x4*)out_h)[i]);

    f32x4 tv = __builtin_nontemporal_load(&ent4[(size_t)tidx * 8 + o]);
    tv.x = tv.x > 0.f ? tv.x : LEAKY * tv.x;
    tv.y = tv.y > 0.f ? tv.y : LEAKY * tv.y;
    tv.z = tv.z > 0.f ? tv.z : LEAKY * tv.z;
    tv.w = tv.w > 0.f ? tv.w : LEAKY * tv.w;
    ((f32x4*)out_t)[i] = tv;                              // cached: ripple reads
}

// ---------------------------------------------------------------------------
// Kernel 4: per-b ripple hops (one wave per b). Unchanged.
// ---------------------------------------------------------------------------
__global__ __launch_bounds__(64) void ripple_kernel(
    const int* __restrict__ pos_items, const float* __restrict__ iEmbed,
    const float* __restrict__ W, const float* __restrict__ Rh,
    const float* __restrict__ t_all, const int* __restrict__ winner,
    float* __restrict__ out_i) {
    int b = blockIdx.x;
    int lane = threadIdx.x;
    int m = lane & 31, half = lane >> 5;

    __shared__ float item[32], pv[32], pre[32];

    int pos = pos_items[b];
    if (lane < 32) item[lane] = iEmbed[(size_t)pos * Dd + lane];
    __syncthreads();

    for (int hop = 0; hop < H; hop++) {
        const float* Rhb = Rh    + (size_t)(hop * B + b) * M * Dd;
        const float* tb  = t_all + (size_t)(hop * B + b) * M * Dd;

        // logits[m] = dot(Rh[m,:], item)
        float partial = 0.f;
        for (int e = half * 16; e < half * 16 + 16; e++)
            partial += Rhb[m * Dd + e] * item[e];
        partial += __shfl_xor(partial, 32, 64);

        // softmax over 32 m
        float mx = partial;
#pragma unroll
        for (int msk = 16; msk >= 1; msk >>= 1)
            mx = fmaxf(mx, __shfl_xor(mx, msk, 64));
        float ex = __expf(partial - mx);
        float sm = ex;
#pragma unroll
        for (int msk = 16; msk >= 1; msk >>= 1)
            sm += __shfl_xor(sm, msk, 64);
        float p = ex / sm;

        if (lane < 32) pv[lane] = p;
        __syncthreads();

        // o[d] = sum_m p[m] * t[m][d]
        float po = 0.f;
        for (int mm = half * 16; mm < half * 16 + 16; mm++)
            po += pv[mm] * tb[mm * Dd + m];
        po += __shfl_xor(po, 32, 64);
        float newpre = item[m] + po;
        __syncthreads();
        if (lane < 32) pre[lane] = newpre;
        __syncthreads();

        // item[d] = sum_e pre[e] * W[d][e]
        float r = 0.f;
        for (int e = half * 16; e < half * 16 + 16; e++)
            r += pre[e] * W[m * Dd + e];
        r += __shfl_xor(r, 32, 64);
        __syncthreads();
        if (lane < 32) item[lane] = r;
        __syncthreads();
    }

    if (winner[pos] == b && lane < 32)
        out_i[(size_t)pos * Dd + lane] = item[lane];
}

// ---------------------------------------------------------------------------
extern "C" void kernel_launch(void* const* d_in, const int* in_sizes, int n_in,
                              void* d_out, int out_size, void* d_ws, size_t ws_size,
                              hipStream_t stream) {
    const int*   pos_items   = (const int*)d_in[0];
    const int*   memories_h  = (const int*)d_in[1];
    const int*   memories_r  = (const int*)d_in[2];
    const int*   memories_t  = (const int*)d_in[3];
    const float* uEmbed      = (const float*)d_in[4];
    const float* iEmbed      = (const float*)d_in[5];
    const float* entity_emb  = (const float*)d_in[6];
    const float* relation_emb= (const float*)d_in[7];
    const float* transform_W = (const float*)d_in[8];

    const int n_user_elems = in_sizes[4];   // USER*D = 3,200,000
    const int n_item_elems = in_sizes[5];   // ITEM*D = 3,200,000
    const int n_items      = n_item_elems / Dd;

    float* out_u = (float*)d_out;
    float* out_i = out_u + n_user_elems;
    float* out_h = out_i + n_item_elems;
    float* out_t = out_h + (size_t)NSLOT * Dd;
    float* out_r = out_t + (size_t)NSLOT * Dd;

    // workspace: winner[ITEM] ints, then Rh[NSLOT*D] floats
    int*   winner = (int*)d_ws;
    float* Rh     = (float*)((char*)d_ws + 512 * 1024);

    // init winner to -1
    (void)hipMemsetAsync(winner, 0xFF, (size_t)n_items * sizeof(int), stream);

    // passthrough copies
    {
        int n4 = n_user_elems / 4;
        int blocks = (n4 + 255) / 256;
        copy_ui_kernel<<<blocks, 256, 0, stream>>>(
            (const f32x4*)uEmbed, (const f32x4*)iEmbed,
            (f32x4*)out_u, (f32x4*)out_i, n4);
    }

    // last-wins winner map
    winner_kernel<<<(B + 255) / 256, 256, 0, stream>>>(pos_items, winner, B);

    // A: flat 537 MB r_all stream + fused Rh
    rcopy_rh_kernel<<<RCOPY_BLOCKS, RCOPY_THREADS, 0, stream>>>(
        memories_r, memories_h, entity_emb, relation_emb, out_r, Rh);

    // B: flat h/t gather (NSLOT*8 f32x4 -> 4096 blocks x 256)
    ht_gather_kernel<<<NSLOT * 8 / 256, 256, 0, stream>>>(
        memories_h, memories_t, entity_emb, out_h, out_t);

    // ripple hops + scatter
    ripple_kernel<<<B, 64, 0, stream>>>(pos_items, iEmbed, transform_W,
                                        Rh, out_t, winner, out_i);
}